// Round 6
// baseline (574.525 us; speedup 1.0000x reference)
//
#include <hip/hip_runtime.h>
#include <cstdint>
#include <cstddef>

// Problem constants (CohereAttention: T=2048, H=4096, NH=32, NKV=8, HD=128)
#define T_SEQ   2048
#define H_DIM   4096
#define NH_Q    32
#define NKV_H   8
#define HD_     128
#define QKV_N   6144            // (NH + 2*NKV) * HD
#define EPS_F   1e-5f
#define ATT_SCALE 0.08838834764831845f   // 1/sqrt(128)
#define LN_THETA  9.210340371976184f     // ln(10000)

typedef __attribute__((ext_vector_type(8))) short bf16x8;
typedef __attribute__((ext_vector_type(4))) float f32x4;

static __device__ __forceinline__ unsigned short f2bf(float f) {
  union { float f; uint32_t u; } v; v.f = f;
  uint32_t u = v.u;
  u += 0x7fff + ((u >> 16) & 1);        // RNE
  return (unsigned short)(u >> 16);
}
static __device__ __forceinline__ float bf2f(unsigned short h) {
  union { uint32_t u; float f; } v; v.u = ((uint32_t)h) << 16;
  return v.f;
}

// async global->LDS, 16B per lane; LDS dest is wave-uniform base + lane*16
static __device__ __forceinline__ void gld_lds16(const void* g, void* l) {
  __builtin_amdgcn_global_load_lds(
      (const __attribute__((address_space(1))) unsigned int*)g,
      (__attribute__((address_space(3))) unsigned int*)l, 16, 0, 0);
}

// ---------------------------------------------------------------------------
// 1) fp32 -> bf16 elementwise convert (hidden_states)
__global__ void convert_bf16_kernel(const float* __restrict__ in,
                                    unsigned short* __restrict__ out, int n4) {
  int i = blockIdx.x * blockDim.x + threadIdx.x;
  if (i < n4) {
    float4 f = *(const float4*)(in + (size_t)i * 4);
    ushort4 o;
    o.x = f2bf(f.x); o.y = f2bf(f.y); o.z = f2bf(f.z); o.w = f2bf(f.w);
    *(ushort4*)(out + (size_t)i * 4) = o;
  }
}

// ---------------------------------------------------------------------------
// 2) fp32 [R][C] -> bf16 [C][R] transpose-convert (weights -> Bt layout)
__global__ void transpose_bf16_kernel(const float* __restrict__ in,
                                      unsigned short* __restrict__ out,
                                      int R, int C) {
  __shared__ float tile[32][33];
  int c0 = blockIdx.x * 32, r0 = blockIdx.y * 32;
  int tx = threadIdx.x, ty = threadIdx.y;   // blockDim = (32, 8)
  for (int i = 0; i < 32; i += 8)
    tile[ty + i][tx] = in[(size_t)(r0 + ty + i) * C + c0 + tx];
  __syncthreads();
  for (int i = 0; i < 32; i += 8)
    out[(size_t)(c0 + ty + i) * R + r0 + tx] = f2bf(tile[tx][ty + i]);
}

// ---------------------------------------------------------------------------
// 3) GEMM 256x256 tile, BK=64, 8 waves (2M x 4N), ONE barrier per K-tile.
//    A bf16 row-major [M][Ks]; Bt = B^T bf16 [N][Ks].
//
//    Hazard proof for the 1-barrier scheme (double-buffered A and B):
//      - a wave's ds_reads of buf[cur] are consumed by MFMAs BEFORE its
//        tile-end barrier (HW lgkm wait precedes MFMA issue), so after the
//        barrier ALL waves have drained buf[cur] -> tile t+1 may overwrite.
//      - staging t+1 into buf[cur^1] right after tile entry is safe: that
//        buffer's readers (tile t-1) finished before the entry barrier.
//      - vmcnt(0) before the barrier guarantees t+1's data landed; it was
//        issued a full tile (~1500 cy) earlier, so the wait is ~free.
//    Interior is one straight-line region: compiler software-pipelines
//    ds_read/MFMA with counted lgkmcnt (m97), waves drift between barriers
//    so LDS reads of one wave overlap MFMAs of another (m114).
//
//    Split-K: blockIdx.z selects K-slice [z*Kl,(z+1)*Kl) and output buffer
//    (z=0 -> C0, z=1 -> C1); caller sums partials.
template <bool BF16OUT>
__global__ __launch_bounds__(512) void gemm256_kernel(
    const unsigned short* __restrict__ A, const unsigned short* __restrict__ Bt,
    void* __restrict__ C0, void* __restrict__ C1,
    int M, int N, int Ks, int Kl) {
  __shared__ unsigned short As[2][256 * 64];
  __shared__ unsigned short Bs[2][256 * 64];
  const int tid = threadIdx.x, lane = tid & 63, wid = tid >> 6;
  const int wm = wid >> 2, wn = wid & 3;        // 2M x 4N wave grid
  const int g = lane >> 4, s = lane & 15, s7 = s & 7;
  const int m0 = blockIdx.y * 256, n0 = blockIdx.x * 256;
  const int z = blockIdx.z;
  const unsigned short* Ab = A + (size_t)z * Kl;   // K-slice base (row stride Ks)
  const unsigned short* Bb = Bt + (size_t)z * Kl;
  void* Cp = z ? C1 : C0;
  const int NT = Kl >> 6;

  // staging: lane l -> row lr = l>>3, chunk lc = l&7; source pre-swizzled
  // (lc ^ lr) so a LINEAR gld_lds dest yields the swizzled LDS layout.
  const int lr = lane >> 3, lc = lane & 7;
  const size_t srcoff = (size_t)lr * Ks + (size_t)((lc ^ lr) * 8);

  auto stage_half = [&](const unsigned short* grow, unsigned short* lhalf) {
    gld_lds16(grow + (size_t)(wid * 16) * Ks + srcoff, lhalf + wid * 1024);
    gld_lds16(grow + (size_t)(wid * 16 + 8) * Ks + srcoff,
              lhalf + wid * 1024 + 512);
  };
  auto stage_tile = [&](int t, unsigned short* dA, unsigned short* dB) {
    const int kk = t << 6;
    stage_half(Ab + (size_t)(m0)       * Ks + kk, dA);
    stage_half(Ab + (size_t)(m0 + 128) * Ks + kk, dA + 128 * 64);
    stage_half(Bb + (size_t)(n0)       * Ks + kk, dB);
    stage_half(Bb + (size_t)(n0 + 128) * Ks + kk, dB + 128 * 64);
  };

  // ds_read offsets (elements): frag at row base + fr*16 + s,
  // chunk (k2*4+g) ^ (row&7); row&7 == s7 since all bases are %16 == 0.
  const int aroff = (wm * 128 + s) * 64;
  const int broff = (wn * 64 + s) * 64;
  const int ck0 = ((0 * 4 + g) ^ s7) * 8;
  const int ck1 = ((1 * 4 + g) ^ s7) * 8;

  f32x4 acc[8][4] = {};

  // ---- prologue: tile 0 into buf0
  stage_tile(0, &As[0][0], &Bs[0][0]);
  asm volatile("s_waitcnt vmcnt(0)" ::: "memory");
  __builtin_amdgcn_s_barrier();

  auto tile_step = [&](unsigned short* cA, unsigned short* cB,
                       unsigned short* nA, unsigned short* nB, int t) {
    // full-tile-distance prefetch of t+1 into the other buffer
    if (t + 1 < NT) stage_tile(t + 1, nA, nB);
    // B fragments for the whole K-tile (8 x ds_read_b128)
    bf16x8 bfr[4][2];
#pragma unroll
    for (int fc = 0; fc < 4; fc++) {
      bfr[fc][0] = *(const bf16x8*)(cB + broff + fc * 1024 + ck0);
      bfr[fc][1] = *(const bf16x8*)(cB + broff + fc * 1024 + ck1);
    }
    // 4 phase-groups, NO interior barriers: compiler pipelines freely
#pragma unroll
    for (int ph = 0; ph < 4; ph++) {
      bf16x8 a[2][2];
#pragma unroll
      for (int i = 0; i < 2; i++) {
        const int fr = ph * 2 + i;
        a[i][0] = *(const bf16x8*)(cA + aroff + fr * 1024 + ck0);
        a[i][1] = *(const bf16x8*)(cA + aroff + fr * 1024 + ck1);
      }
      __builtin_amdgcn_s_setprio(1);
#pragma unroll
      for (int i = 0; i < 2; i++) {
        const int fr = ph * 2 + i;
#pragma unroll
        for (int fc = 0; fc < 4; fc++)
          acc[fr][fc] = __builtin_amdgcn_mfma_f32_16x16x32_bf16(
              a[i][0], bfr[fc][0], acc[fr][fc], 0, 0, 0);
      }
#pragma unroll
      for (int i = 0; i < 2; i++) {
        const int fr = ph * 2 + i;
#pragma unroll
        for (int fc = 0; fc < 4; fc++)
          acc[fr][fc] = __builtin_amdgcn_mfma_f32_16x16x32_bf16(
              a[i][1], bfr[fc][1], acc[fr][fc], 0, 0, 0);
      }
      __builtin_amdgcn_s_setprio(0);
    }
    // t+1 landed (issued a full tile ago); single sync point per K-tile
    asm volatile("s_waitcnt vmcnt(0)" ::: "memory");
    __builtin_amdgcn_s_barrier();
  };

  for (int t = 0; t < NT; t += 2) {
    tile_step(&As[0][0], &Bs[0][0], &As[1][0], &Bs[1][0], t);
    tile_step(&As[1][0], &Bs[1][0], &As[0][0], &Bs[0][0], t + 1);
  }

  // ---- epilogue: C/D layout row = g*4 + r, col = s (per 16x16 fragment)
#pragma unroll
  for (int fr = 0; fr < 8; fr++)
#pragma unroll
    for (int fc = 0; fc < 4; fc++)
#pragma unroll
      for (int r = 0; r < 4; r++) {
        int m = m0 + wm * 128 + fr * 16 + g * 4 + r;
        int n = n0 + wn * 64 + fc * 16 + s;
        float v = acc[fr][fc][r];
        if (BF16OUT) ((unsigned short*)Cp)[(size_t)m * N + n] = f2bf(v);
        else         ((float*)Cp)[(size_t)m * N + n] = v;
      }
}

// ---------------------------------------------------------------------------
// 3b) split-K reduction: out += part  (float4)
__global__ void addf_kernel(float* __restrict__ o, const float* __restrict__ p,
                            int n4) {
  int i = blockIdx.x * blockDim.x + threadIdx.x;
  if (i < n4) {
    float4 a = *(const float4*)(o + (size_t)i * 4);
    float4 b = *(const float4*)(p + (size_t)i * 4);
    a.x += b.x; a.y += b.y; a.z += b.z; a.w += b.w;
    *(float4*)(o + (size_t)i * 4) = a;
  }
}

// ---------------------------------------------------------------------------
// 4) Per-(t,head) LayerNorm + interleaved RoPE, in-place on qkv buffer.
__global__ __launch_bounds__(256) void ln_rope_kernel(
    unsigned short* __restrict__ qkv, const int* __restrict__ positions,
    const float* __restrict__ qw, const float* __restrict__ kw) {
  const int wid = threadIdx.x >> 6, lane = threadIdx.x & 63;
  const int rid = blockIdx.x * 4 + wid;     // 0 .. T*(NH+NKV)-1
  const int t = rid / 40, hh = rid % 40;
  const bool isq = hh < NH_Q;
  const int col = isq ? hh * HD_ : H_DIM + (hh - NH_Q) * HD_;
  unsigned short* row = qkv + (size_t)t * QKV_N + col;

  uint32_t both = *(const uint32_t*)(row + lane * 2);
  float x1 = bf2f((unsigned short)(both & 0xffff));
  float x2 = bf2f((unsigned short)(both >> 16));
  float ssum = x1 + x2, ssq = x1 * x1 + x2 * x2;
  for (int off = 1; off < 64; off <<= 1) {
    ssum += __shfl_xor(ssum, off, 64);
    ssq  += __shfl_xor(ssq,  off, 64);
  }
  float mean = ssum * (1.0f / HD_);
  float var  = ssq * (1.0f / HD_) - mean * mean;
  float rs = rsqrtf(var + EPS_F);
  const float* w = isq ? (qw + hh * HD_) : (kw + (hh - NH_Q) * HD_);
  float2 wv = *(const float2*)(w + lane * 2);
  float y1 = (x1 - mean) * rs * wv.x;
  float y2 = (x2 - mean) * rs * wv.y;
  float pos = (float)positions[t];
  float inv = __expf(-((float)(2 * lane) * (1.0f / HD_)) * LN_THETA);
  float fr = pos * inv;
  float c = cosf(fr), sn = sinf(fr);
  float o1 = y1 * c - y2 * sn;
  float o2 = y2 * c + y1 * sn;
  if (isq) { o1 *= ATT_SCALE; o2 *= ATT_SCALE; }
  *(uint32_t*)(row + lane * 2) =
      (uint32_t)f2bf(o1) | ((uint32_t)f2bf(o2) << 16);
}

// ---------------------------------------------------------------------------
// 5) V transpose: qkv v-part [t][kvh*128+hd] -> Vt[kvh][hd][t] (bf16)
__global__ void vt_kernel(const unsigned short* __restrict__ qkv,
                          unsigned short* __restrict__ vt) {
  __shared__ unsigned short tile[32][33];
  const int kvh = blockIdx.z;
  const int t0 = blockIdx.x * 32, d0 = blockIdx.y * 32;
  const int tx = threadIdx.x, ty = threadIdx.y;   // (32, 8)
  for (int i = 0; i < 32; i += 8)
    tile[ty + i][tx] =
        qkv[(size_t)(t0 + ty + i) * QKV_N + H_DIM + NKV_H * HD_ + kvh * HD_ + d0 + tx];
  __syncthreads();
  for (int i = 0; i < 32; i += 8)
    vt[((size_t)kvh * HD_ + d0 + ty + i) * T_SEQ + t0 + tx] = tile[tx][ty + i];
}

// ---------------------------------------------------------------------------
// 6) Flash attention: block = (64-row Q-tile, head); 4 waves x 16 Q-rows.
//    Load balance: block bx processes qt=bx AND qt=NQT-1-bx (uniform work).
__global__ __launch_bounds__(256) void attn_kernel(
    const unsigned short* __restrict__ qkv, const unsigned short* __restrict__ vt,
    unsigned short* __restrict__ out) {
  __shared__ unsigned short Ks[64 * 136];    // K-tile  [key][hd], pad 128->136
  __shared__ unsigned short Vs[128 * 72];    // Vt-tile [hd][key], pad 64->72
  __shared__ unsigned short Ps[4][16 * 72];  // per-wave P  [qrow][key]
  const int tid = threadIdx.x, lane = tid & 63, wid = tid >> 6;
  const int g = lane >> 4, s = lane & 15;
  const int h = blockIdx.y;
  const int kvh = h >> 2;                    // GQA: 4 q-heads per kv-head
  const int NQT = T_SEQ / 64;

  for (int half = 0; half < 2; half++) {
    const int qt = (half == 0) ? (int)blockIdx.x : NQT - 1 - (int)blockIdx.x;
    const int q0 = qt * 64;

    bf16x8 qf[4];
    {
      const unsigned short* qrow =
          qkv + (size_t)(q0 + wid * 16 + s) * QKV_N + h * HD_;
      for (int ks = 0; ks < 4; ks++)
        qf[ks] = *(const bf16x8*)(qrow + ks * 32 + g * 8);
    }
    f32x4 o[8] = {};
    float m_i[4], l_i[4];
    for (int r = 0; r < 4; r++) { m_i[r] = -1e30f; l_i[r] = 0.f; }

    const int ktiles = qt + 1;
    for (int kt = 0; kt < ktiles; kt++) {
      const int k0 = kt * 64;
      __syncthreads();   // previous iter's PV reads of Ks/Vs done
      {
        int kr = tid >> 4, kc = tid & 15;      // K: 16 lanes/row x 16B
        for (int p = 0; p < 4; p++) {
          bf16x8 v = *(const bf16x8*)(qkv + (size_t)(k0 + kr + p * 16) * QKV_N +
                                      H_DIM + kvh * HD_ + kc * 8);
          *(bf16x8*)&Ks[(kr + p * 16) * 136 + kc * 8] = v;
        }
        int vr = tid >> 3, vc = tid & 7;       // Vt: 8 lanes/row x 16B
        for (int p = 0; p < 4; p++) {
          bf16x8 v = *(const bf16x8*)(vt + ((size_t)kvh * HD_ + vr + p * 32) * T_SEQ +
                                      k0 + vc * 8);
          *(bf16x8*)&Vs[(vr + p * 32) * 72 + vc * 8] = v;
        }
      }
      __syncthreads();
      f32x4 sa[4] = {};
      __builtin_amdgcn_s_setprio(1);
      for (int nt = 0; nt < 4; nt++)
        for (int ks = 0; ks < 4; ks++) {
          bf16x8 kb = *(const bf16x8*)&Ks[(nt * 16 + s) * 136 + ks * 32 + g * 8];
          sa[nt] = __builtin_amdgcn_mfma_f32_16x16x32_bf16(qf[ks], kb, sa[nt], 0, 0, 0);
        }
      __builtin_amdgcn_s_setprio(0);
      if (kt == ktiles - 1) {   // causal mask only ever clips the diagonal tile
        for (int nt = 0; nt < 4; nt++)
          for (int r = 0; r < 4; r++)
            if (k0 + nt * 16 + s > q0 + wid * 16 + g * 4 + r) sa[nt][r] = -1e30f;
      }
      float alpha[4];
      for (int r = 0; r < 4; r++) {
        float mx = fmaxf(fmaxf(sa[0][r], sa[1][r]), fmaxf(sa[2][r], sa[3][r]));
        for (int off = 1; off < 16; off <<= 1) mx = fmaxf(mx, __shfl_xor(mx, off, 64));
        float mn = fmaxf(m_i[r], mx);
        alpha[r] = __expf(m_i[r] - mn);
        m_i[r] = mn;
        float rsum = 0.f;
        for (int nt = 0; nt < 4; nt++) {
          float p = __expf(sa[nt][r] - mn);
          sa[nt][r] = p;
          rsum += p;
        }
        for (int off = 1; off < 16; off <<= 1) rsum += __shfl_xor(rsum, off, 64);
        l_i[r] = l_i[r] * alpha[r] + rsum;
      }
      for (int nt = 0; nt < 4; nt++)          // P -> LDS (C-layout -> A-layout)
        for (int r = 0; r < 4; r++)
          Ps[wid][(g * 4 + r) * 72 + nt * 16 + s] = f2bf(sa[nt][r]);
      for (int ot = 0; ot < 8; ot++)
        for (int r = 0; r < 4; r++) o[ot][r] *= alpha[r];
      __syncthreads();   // Ps visible (and orders same-wave LDS RAW)
      __builtin_amdgcn_s_setprio(1);
      for (int ot = 0; ot < 8; ot++)
        for (int ks = 0; ks < 2; ks++) {
          bf16x8 pa = *(const bf16x8*)&Ps[wid][s * 72 + ks * 32 + g * 8];
          bf16x8 vb = *(const bf16x8*)&Vs[(ot * 16 + s) * 72 + ks * 32 + g * 8];
          o[ot] = __builtin_amdgcn_mfma_f32_16x16x32_bf16(pa, vb, o[ot], 0, 0, 0);
        }
      __builtin_amdgcn_s_setprio(0);
    }
    const size_t obase = (size_t)(q0 + wid * 16);
    for (int ot = 0; ot < 8; ot++)
      for (int r = 0; r < 4; r++) {
        float v = o[ot][r] / l_i[r];
        out[(obase + g * 4 + r) * (size_t)(NH_Q * HD_) + h * HD_ + ot * 16 + s] =
            f2bf(v);
      }
  }
}

// ---------------------------------------------------------------------------
extern "C" void kernel_launch(void* const* d_in, const int* in_sizes, int n_in,
                              void* d_out, int out_size, void* d_ws, size_t ws_size,
                              hipStream_t stream) {
  const int*   positions = (const int*)d_in[0];
  const float* hs        = (const float*)d_in[1];
  const float* w_qkv     = (const float*)d_in[2];
  const float* w_o       = (const float*)d_in[3];
  const float* q_norm_w  = (const float*)d_in[4];
  const float* k_norm_w  = (const float*)d_in[5];
  float* out = (float*)d_out;

  // workspace carve-up (total ~140 MiB)
  char* p = (char*)d_ws;
  unsigned short* hsb   = (unsigned short*)p; p += (size_t)T_SEQ * H_DIM * 2;      // 16M
  unsigned short* wqkvT = (unsigned short*)p; p += (size_t)QKV_N * H_DIM * 2;      // 48M
  unsigned short* woT   = (unsigned short*)p; p += (size_t)H_DIM * H_DIM * 2;      // 32M
  unsigned short* qkvb  = (unsigned short*)p; p += (size_t)T_SEQ * QKV_N * 2;      // 24M
  unsigned short* attnb = (unsigned short*)p; p += (size_t)T_SEQ * H_DIM * 2;      // 16M
  unsigned short* vtb   = (unsigned short*)p; p += (size_t)NKV_H * HD_ * T_SEQ * 2; // 4M
  // split-K partial for O-proj: reuses wqkvT (dead after QKV GEMM), 32M <= 48M
  float* part1 = (float*)wqkvT;

  // 1) converts / transposes
  convert_bf16_kernel<<<(T_SEQ * H_DIM / 4 + 255) / 256, 256, 0, stream>>>(
      hs, hsb, T_SEQ * H_DIM / 4);
  transpose_bf16_kernel<<<dim3(QKV_N / 32, H_DIM / 32), dim3(32, 8), 0, stream>>>(
      w_qkv, wqkvT, H_DIM, QKV_N);
  transpose_bf16_kernel<<<dim3(H_DIM / 32, H_DIM / 32), dim3(32, 8), 0, stream>>>(
      w_o, woT, H_DIM, H_DIM);
  // 2) QKV projection (256^2, full K)
  gemm256_kernel<true><<<dim3(QKV_N / 256, T_SEQ / 256, 1), 512, 0, stream>>>(
      hsb, wqkvT, qkvb, nullptr, T_SEQ, QKV_N, H_DIM, H_DIM);
  // 3) LN + RoPE (in place; q also scaled by 1/sqrt(HD))
  ln_rope_kernel<<<T_SEQ * (NH_Q + NKV_H) / 4, 256, 0, stream>>>(
      qkvb, positions, q_norm_w, k_norm_w);
  // 4) V transpose for PV B-operand
  vt_kernel<<<dim3(T_SEQ / 32, HD_ / 32, NKV_H), dim3(32, 8), 0, stream>>>(qkvb, vtb);
  // 5) flash attention (paired Q-tiles: uniform work per block)
  attn_kernel<<<dim3(T_SEQ / 128, NH_Q), 256, 0, stream>>>(qkvb, vtb, attnb);
  // 6) output projection, split-K=2: grid 16x8x2 = 256 blocks (full coverage)
  gemm256_kernel<false><<<dim3(H_DIM / 256, T_SEQ / 256, 2), 512, 0, stream>>>(
      attnb, woT, out, part1, T_SEQ, H_DIM, H_DIM, H_DIM / 2);
  addf_kernel<<<(T_SEQ * H_DIM / 4 + 255) / 256, 256, 0, stream>>>(
      out, part1, T_SEQ * H_DIM / 4);
}

// Round 7
// 569.427 us; speedup vs baseline: 1.0090x; 1.0090x over previous
//
#include <hip/hip_runtime.h>
#include <cstdint>
#include <cstddef>

// Problem constants (CohereAttention: T=2048, H=4096, NH=32, NKV=8, HD=128)
#define T_SEQ   2048
#define H_DIM   4096
#define NH_Q    32
#define NKV_H   8
#define HD_     128
#define QKV_N   6144            // (NH + 2*NKV) * HD
#define EPS_F   1e-5f
#define ATT_SCALE 0.08838834764831845f   // 1/sqrt(128)
#define LN_THETA  9.210340371976184f     // ln(10000)

typedef __attribute__((ext_vector_type(8))) short bf16x8;
typedef __attribute__((ext_vector_type(4))) float f32x4;

static __device__ __forceinline__ unsigned short f2bf(float f) {
  union { float f; uint32_t u; } v; v.f = f;
  uint32_t u = v.u;
  u += 0x7fff + ((u >> 16) & 1);        // RNE
  return (unsigned short)(u >> 16);
}
static __device__ __forceinline__ float bf2f(unsigned short h) {
  union { uint32_t u; float f; } v; v.u = ((uint32_t)h) << 16;
  return v.f;
}

// async global->LDS, 16B per lane; LDS dest is wave-uniform base + lane*16
static __device__ __forceinline__ void gld_lds16(const void* g, void* l) {
  __builtin_amdgcn_global_load_lds(
      (const __attribute__((address_space(1))) unsigned int*)g,
      (__attribute__((address_space(3))) unsigned int*)l, 16, 0, 0);
}

// ---------------------------------------------------------------------------
// 1) fp32 -> bf16 elementwise convert (hidden_states)
__global__ void convert_bf16_kernel(const float* __restrict__ in,
                                    unsigned short* __restrict__ out, int n4) {
  int i = blockIdx.x * blockDim.x + threadIdx.x;
  if (i < n4) {
    float4 f = *(const float4*)(in + (size_t)i * 4);
    ushort4 o;
    o.x = f2bf(f.x); o.y = f2bf(f.y); o.z = f2bf(f.z); o.w = f2bf(f.w);
    *(ushort4*)(out + (size_t)i * 4) = o;
  }
}

// ---------------------------------------------------------------------------
// 2) fp32 [R][C] -> bf16 [C][R] transpose-convert, 64x64 tile, float4 reads
//    + ushort4 writes (G13: scalar 4B loads ~2x slower on BW-bound passes).
__global__ __launch_bounds__(256) void transpose_bf16_kernel(
    const float* __restrict__ in, unsigned short* __restrict__ out,
    int R, int C) {
  __shared__ float tile[64][65];
  const int c0 = blockIdx.x * 64, r0 = blockIdx.y * 64;
  const int tx = threadIdx.x, ty = threadIdx.y;   // blockDim = (16, 16)
  for (int i = 0; i < 64; i += 16) {
    float4 v = *(const float4*)(in + (size_t)(r0 + ty + i) * C + c0 + tx * 4);
    tile[ty + i][tx * 4 + 0] = v.x;
    tile[ty + i][tx * 4 + 1] = v.y;
    tile[ty + i][tx * 4 + 2] = v.z;
    tile[ty + i][tx * 4 + 3] = v.w;
  }
  __syncthreads();
  for (int i = 0; i < 64; i += 16) {
    ushort4 o4;
    o4.x = f2bf(tile[tx * 4 + 0][ty + i]);
    o4.y = f2bf(tile[tx * 4 + 1][ty + i]);
    o4.z = f2bf(tile[tx * 4 + 2][ty + i]);
    o4.w = f2bf(tile[tx * 4 + 3][ty + i]);
    *(ushort4*)(out + (size_t)(c0 + ty + i) * R + r0 + tx * 4) = o4;
  }
}

// ---------------------------------------------------------------------------
// 3) GEMM 256x256 tile, BK=64, 8 waves (2M x 4N), 4-phase counted-vmcnt
//    schedule (R5 config: best measured, QKV=130us). Split-K via blockIdx.z.
template <bool BF16OUT>
__global__ __launch_bounds__(512) void gemm256_kernel(
    const unsigned short* __restrict__ A, const unsigned short* __restrict__ Bt,
    void* __restrict__ C0, void* __restrict__ C1,
    int M, int N, int Ks, int Kl) {
  __shared__ unsigned short As[2][256 * 64];
  __shared__ unsigned short Bs[2][256 * 64];
  const int tid = threadIdx.x, lane = tid & 63, wid = tid >> 6;
  const int wm = wid >> 2, wn = wid & 3;        // 2M x 4N wave grid
  const int g = lane >> 4, s = lane & 15, s7 = s & 7;
  const int m0 = blockIdx.y * 256, n0 = blockIdx.x * 256;
  const int z = blockIdx.z;
  const unsigned short* Ab = A + (size_t)z * Kl;   // K-slice base (row stride Ks)
  const unsigned short* Bb = Bt + (size_t)z * Kl;
  void* Cp = z ? C1 : C0;
  const int NT = Kl >> 6;

  // staging: lane l -> row lr = l>>3, chunk lc = l&7; source pre-swizzled
  // (lc ^ lr) so a LINEAR gld_lds dest yields the swizzled LDS layout.
  const int lr = lane >> 3, lc = lane & 7;
  const size_t srcoff = (size_t)lr * Ks + (size_t)((lc ^ lr) * 8);

  auto stage_half = [&](const unsigned short* grow, unsigned short* lhalf) {
    gld_lds16(grow + (size_t)(wid * 16) * Ks + srcoff, lhalf + wid * 1024);
    gld_lds16(grow + (size_t)(wid * 16 + 8) * Ks + srcoff,
              lhalf + wid * 1024 + 512);
  };

  // ds_read offsets (elements): frag at row base + fr*16 + s,
  // chunk (k2*4+g) ^ (row&7); row&7 == s7 since all bases are %16 == 0.
  const int aroff = (wm * 128 + s) * 64;
  const int broff = (wn * 64 + s) * 64;
  const int ck0 = ((0 * 4 + g) ^ s7) * 8;
  const int ck1 = ((1 * 4 + g) ^ s7) * 8;

  f32x4 acc[8][4] = {};

  // ---- prologue: A(0), B(0), B(1); vmcnt(4) leaves B(1) in flight
  stage_half(Ab + (size_t)(m0)       * Ks, &As[0][0]);
  stage_half(Ab + (size_t)(m0 + 128) * Ks, &As[0][128 * 64]);
  stage_half(Bb + (size_t)(n0)       * Ks, &Bs[0][0]);
  stage_half(Bb + (size_t)(n0 + 128) * Ks, &Bs[0][128 * 64]);
  stage_half(Bb + (size_t)(n0)       * Ks + 64, &Bs[1][0]);
  stage_half(Bb + (size_t)(n0 + 128) * Ks + 64, &Bs[1][128 * 64]);
  asm volatile("s_waitcnt vmcnt(4)" ::: "memory");
  __builtin_amdgcn_s_barrier();

  auto tile_step = [&](unsigned short* cA, unsigned short* cB,
                       unsigned short* nA, int t) {
    const int k0 = t << 6;
    // B fragments for the whole K-tile (8 x ds_read_b128), read in phase 0
    bf16x8 bfr[4][2];
#pragma unroll
    for (int fc = 0; fc < 4; fc++) {
      bfr[fc][0] = *(const bf16x8*)(cB + broff + fc * 1024 + ck0);
      bfr[fc][1] = *(const bf16x8*)(cB + broff + fc * 1024 + ck1);
    }
#pragma unroll
    for (int ph = 0; ph < 4; ph++) {
      bf16x8 a[2][2];
#pragma unroll
      for (int i = 0; i < 2; i++) {
        const int fr = ph * 2 + i;
        a[i][0] = *(const bf16x8*)(cA + aroff + fr * 1024 + ck0);
        a[i][1] = *(const bf16x8*)(cA + aroff + fr * 1024 + ck1);
      }
      if (ph == 0 && t + 1 < NT)
        stage_half(Ab + (size_t)(m0) * Ks + k0 + 64, nA);
      if (ph == 1 && t + 1 < NT)
        stage_half(Ab + (size_t)(m0 + 128) * Ks + k0 + 64, nA + 128 * 64);
      if (ph == 2 && t + 2 < NT)
        stage_half(Bb + (size_t)(n0) * Ks + k0 + 128, cB);
      if (ph == 3 && t + 2 < NT)
        stage_half(Bb + (size_t)(n0 + 128) * Ks + k0 + 128, cB + 128 * 64);
      __builtin_amdgcn_s_barrier();
      __builtin_amdgcn_s_setprio(1);
      // all k2=0 MFMAs first, then k2=1 (no dependent back-to-back pairs)
#pragma unroll
      for (int i = 0; i < 2; i++) {
        const int fr = ph * 2 + i;
#pragma unroll
        for (int fc = 0; fc < 4; fc++)
          acc[fr][fc] = __builtin_amdgcn_mfma_f32_16x16x32_bf16(
              a[i][0], bfr[fc][0], acc[fr][fc], 0, 0, 0);
      }
#pragma unroll
      for (int i = 0; i < 2; i++) {
        const int fr = ph * 2 + i;
#pragma unroll
        for (int fc = 0; fc < 4; fc++)
          acc[fr][fc] = __builtin_amdgcn_mfma_f32_16x16x32_bf16(
              a[i][1], bfr[fc][1], acc[fr][fc], 0, 0, 0);
      }
      __builtin_amdgcn_s_setprio(0);
      if (ph == 3) {
        if (t + 2 < NT) asm volatile("s_waitcnt vmcnt(4)" ::: "memory");
        else            asm volatile("s_waitcnt vmcnt(0)" ::: "memory");
      }
      __builtin_amdgcn_s_barrier();
    }
  };

  for (int t = 0; t < NT; t += 2) {
    tile_step(&As[0][0], &Bs[0][0], &As[1][0], t);
    tile_step(&As[1][0], &Bs[1][0], &As[0][0], t + 1);
  }

  // ---- epilogue: C/D layout row = g*4 + r, col = s (per 16x16 fragment)
#pragma unroll
  for (int fr = 0; fr < 8; fr++)
#pragma unroll
    for (int fc = 0; fc < 4; fc++)
#pragma unroll
      for (int r = 0; r < 4; r++) {
        int m = m0 + wm * 128 + fr * 16 + g * 4 + r;
        int n = n0 + wn * 64 + fc * 16 + s;
        float v = acc[fr][fc][r];
        if (BF16OUT) ((unsigned short*)Cp)[(size_t)m * N + n] = f2bf(v);
        else         ((float*)Cp)[(size_t)m * N + n] = v;
      }
}

// ---------------------------------------------------------------------------
// 3b) split-K reduction: out += part  (float4)
__global__ void addf_kernel(float* __restrict__ o, const float* __restrict__ p,
                            int n4) {
  int i = blockIdx.x * blockDim.x + threadIdx.x;
  if (i < n4) {
    float4 a = *(const float4*)(o + (size_t)i * 4);
    float4 b = *(const float4*)(p + (size_t)i * 4);
    a.x += b.x; a.y += b.y; a.z += b.z; a.w += b.w;
    *(float4*)(o + (size_t)i * 4) = a;
  }
}

// ---------------------------------------------------------------------------
// 4) Per-(t,head) LayerNorm + interleaved RoPE, in-place on qkv buffer.
__global__ __launch_bounds__(256) void ln_rope_kernel(
    unsigned short* __restrict__ qkv, const int* __restrict__ positions,
    const float* __restrict__ qw, const float* __restrict__ kw) {
  const int wid = threadIdx.x >> 6, lane = threadIdx.x & 63;
  const int rid = blockIdx.x * 4 + wid;     // 0 .. T*(NH+NKV)-1
  const int t = rid / 40, hh = rid % 40;
  const bool isq = hh < NH_Q;
  const int col = isq ? hh * HD_ : H_DIM + (hh - NH_Q) * HD_;
  unsigned short* row = qkv + (size_t)t * QKV_N + col;

  uint32_t both = *(const uint32_t*)(row + lane * 2);
  float x1 = bf2f((unsigned short)(both & 0xffff));
  float x2 = bf2f((unsigned short)(both >> 16));
  float ssum = x1 + x2, ssq = x1 * x1 + x2 * x2;
  for (int off = 1; off < 64; off <<= 1) {
    ssum += __shfl_xor(ssum, off, 64);
    ssq  += __shfl_xor(ssq,  off, 64);
  }
  float mean = ssum * (1.0f / HD_);
  float var  = ssq * (1.0f / HD_) - mean * mean;
  float rs = rsqrtf(var + EPS_F);
  const float* w = isq ? (qw + hh * HD_) : (kw + (hh - NH_Q) * HD_);
  float2 wv = *(const float2*)(w + lane * 2);
  float y1 = (x1 - mean) * rs * wv.x;
  float y2 = (x2 - mean) * rs * wv.y;
  float pos = (float)positions[t];
  float inv = __expf(-((float)(2 * lane) * (1.0f / HD_)) * LN_THETA);
  float fr = pos * inv;
  float c = cosf(fr), sn = sinf(fr);
  float o1 = y1 * c - y2 * sn;
  float o2 = y2 * c + y1 * sn;
  if (isq) { o1 *= ATT_SCALE; o2 *= ATT_SCALE; }
  *(uint32_t*)(row + lane * 2) =
      (uint32_t)f2bf(o1) | ((uint32_t)f2bf(o2) << 16);
}

// ---------------------------------------------------------------------------
// 5) V transpose: qkv v-part [t][kvh*128+hd] -> Vt[kvh][hd][t] (bf16)
__global__ void vt_kernel(const unsigned short* __restrict__ qkv,
                          unsigned short* __restrict__ vt) {
  __shared__ unsigned short tile[32][33];
  const int kvh = blockIdx.z;
  const int t0 = blockIdx.x * 32, d0 = blockIdx.y * 32;
  const int tx = threadIdx.x, ty = threadIdx.y;   // (32, 8)
  for (int i = 0; i < 32; i += 8)
    tile[ty + i][tx] =
        qkv[(size_t)(t0 + ty + i) * QKV_N + H_DIM + NKV_H * HD_ + kvh * HD_ + d0 + tx];
  __syncthreads();
  for (int i = 0; i < 32; i += 8)
    vt[((size_t)kvh * HD_ + d0 + ty + i) * T_SEQ + t0 + tx] = tile[tx][ty + i];
}

// ---------------------------------------------------------------------------
// 6) Flash attention: block = (128-row Q-tile, head); 8 waves x 16 Q-rows.
//    K/V staged once per 64-key tile serve 2x the Q-work (vs QBLK=64):
//    staging bytes/FLOP and barriers/FLOP halve. Grid 8x32 = 256 blocks
//    (1/CU, full coverage); pairing qt=bx & NQT-1-bx keeps work uniform
//    (34 K-steps per block). Causal mask clips the last TWO K-tiles (the
//    128 Q-rows span 2 key-tiles); fully-masked rows contribute exp->0.
__global__ __launch_bounds__(512) void attn_kernel(
    const unsigned short* __restrict__ qkv, const unsigned short* __restrict__ vt,
    unsigned short* __restrict__ out) {
  __shared__ unsigned short Ks[64 * 136];    // K-tile  [key][hd], pad 128->136
  __shared__ unsigned short Vs[128 * 72];    // Vt-tile [hd][key], pad 64->72
  __shared__ unsigned short Ps[8][16 * 72];  // per-wave P  [qrow][key]
  const int tid = threadIdx.x, lane = tid & 63, wid = tid >> 6;
  const int g = lane >> 4, s = lane & 15;
  const int h = blockIdx.y;
  const int kvh = h >> 2;                    // GQA: 4 q-heads per kv-head
  const int NQT = T_SEQ / 128;               // 16

  for (int half = 0; half < 2; half++) {
    const int qt = (half == 0) ? (int)blockIdx.x : NQT - 1 - (int)blockIdx.x;
    const int q0 = qt * 128;

    // Q fragments direct from global (A-layout: m=lane&15, k=(lane>>4)*8+j)
    bf16x8 qf[4];
    {
      const unsigned short* qrow =
          qkv + (size_t)(q0 + wid * 16 + s) * QKV_N + h * HD_;
      for (int ks = 0; ks < 4; ks++)
        qf[ks] = *(const bf16x8*)(qrow + ks * 32 + g * 8);
    }
    f32x4 o[8] = {};
    float m_i[4], l_i[4];
    for (int r = 0; r < 4; r++) { m_i[r] = -1e30f; l_i[r] = 0.f; }

    const int ktiles = 2 * qt + 2;
    for (int kt = 0; kt < ktiles; kt++) {
      const int k0 = kt * 64;
      __syncthreads();   // previous iter's PV reads of Ks/Vs done
      {
        int kr = tid >> 4, kc = tid & 15;      // K: 512 thr = 32 rows x 16B x2
        for (int p = 0; p < 2; p++) {
          bf16x8 v = *(const bf16x8*)(qkv + (size_t)(k0 + kr + p * 32) * QKV_N +
                                      H_DIM + kvh * HD_ + kc * 8);
          *(bf16x8*)&Ks[(kr + p * 32) * 136 + kc * 8] = v;
        }
        int vr = tid >> 3, vc = tid & 7;       // Vt: 64 rows x 8x16B x2
        for (int p = 0; p < 2; p++) {
          bf16x8 v = *(const bf16x8*)(vt + ((size_t)kvh * HD_ + vr + p * 64) * T_SEQ +
                                      k0 + vc * 8);
          *(bf16x8*)&Vs[(vr + p * 64) * 72 + vc * 8] = v;
        }
      }
      __syncthreads();
      // S = Q*K^T  (4 key-subtiles x 4 k-steps)
      f32x4 sa[4] = {};
      __builtin_amdgcn_s_setprio(1);
      for (int nt = 0; nt < 4; nt++)
        for (int ks = 0; ks < 4; ks++) {
          bf16x8 kb = *(const bf16x8*)&Ks[(nt * 16 + s) * 136 + ks * 32 + g * 8];
          sa[nt] = __builtin_amdgcn_mfma_f32_16x16x32_bf16(qf[ks], kb, sa[nt], 0, 0, 0);
        }
      __builtin_amdgcn_s_setprio(0);
      if (kt >= ktiles - 2) {   // causal mask clips the last two key-tiles
        for (int nt = 0; nt < 4; nt++)
          for (int r = 0; r < 4; r++)
            if (k0 + nt * 16 + s > q0 + wid * 16 + g * 4 + r) sa[nt][r] = -1e30f;
      }
      // online softmax (rows live across the 16 lanes of each quad-group)
      float alpha[4];
      for (int r = 0; r < 4; r++) {
        float mx = fmaxf(fmaxf(sa[0][r], sa[1][r]), fmaxf(sa[2][r], sa[3][r]));
        for (int off = 1; off < 16; off <<= 1) mx = fmaxf(mx, __shfl_xor(mx, off, 64));
        float mn = fmaxf(m_i[r], mx);
        alpha[r] = __expf(m_i[r] - mn);
        m_i[r] = mn;
        float rsum = 0.f;
        for (int nt = 0; nt < 4; nt++) {
          float p = __expf(sa[nt][r] - mn);
          sa[nt][r] = p;
          rsum += p;
        }
        for (int off = 1; off < 16; off <<= 1) rsum += __shfl_xor(rsum, off, 64);
        l_i[r] = l_i[r] * alpha[r] + rsum;
      }
      for (int nt = 0; nt < 4; nt++)          // P -> LDS (C-layout -> A-layout)
        for (int r = 0; r < 4; r++)
          Ps[wid][(g * 4 + r) * 72 + nt * 16 + s] = f2bf(sa[nt][r]);
      for (int ot = 0; ot < 8; ot++)
        for (int r = 0; r < 4; r++) o[ot][r] *= alpha[r];
      __syncthreads();   // Ps visible (and orders same-wave LDS RAW)
      // O += P*V
      __builtin_amdgcn_s_setprio(1);
      for (int ot = 0; ot < 8; ot++)
        for (int ks = 0; ks < 2; ks++) {
          bf16x8 pa = *(const bf16x8*)&Ps[wid][s * 72 + ks * 32 + g * 8];
          bf16x8 vb = *(const bf16x8*)&Vs[(ot * 16 + s) * 72 + ks * 32 + g * 8];
          o[ot] = __builtin_amdgcn_mfma_f32_16x16x32_bf16(pa, vb, o[ot], 0, 0, 0);
        }
      __builtin_amdgcn_s_setprio(0);
    }
    const size_t obase = (size_t)(q0 + wid * 16);
    for (int ot = 0; ot < 8; ot++)
      for (int r = 0; r < 4; r++) {
        float v = o[ot][r] / l_i[r];
        out[(obase + g * 4 + r) * (size_t)(NH_Q * HD_) + h * HD_ + ot * 16 + s] =
            f2bf(v);
      }
  }
}

// ---------------------------------------------------------------------------
extern "C" void kernel_launch(void* const* d_in, const int* in_sizes, int n_in,
                              void* d_out, int out_size, void* d_ws, size_t ws_size,
                              hipStream_t stream) {
  const int*   positions = (const int*)d_in[0];
  const float* hs        = (const float*)d_in[1];
  const float* w_qkv     = (const float*)d_in[2];
  const float* w_o       = (const float*)d_in[3];
  const float* q_norm_w  = (const float*)d_in[4];
  const float* k_norm_w  = (const float*)d_in[5];
  float* out = (float*)d_out;

  // workspace carve-up (total ~140 MiB)
  char* p = (char*)d_ws;
  unsigned short* hsb   = (unsigned short*)p; p += (size_t)T_SEQ * H_DIM * 2;      // 16M
  unsigned short* wqkvT = (unsigned short*)p; p += (size_t)QKV_N * H_DIM * 2;      // 48M
  unsigned short* woT   = (unsigned short*)p; p += (size_t)H_DIM * H_DIM * 2;      // 32M
  unsigned short* qkvb  = (unsigned short*)p; p += (size_t)T_SEQ * QKV_N * 2;      // 24M
  unsigned short* attnb = (unsigned short*)p; p += (size_t)T_SEQ * H_DIM * 2;      // 16M
  unsigned short* vtb   = (unsigned short*)p; p += (size_t)NKV_H * HD_ * T_SEQ * 2; // 4M
  // split-K partial for O-proj: reuses wqkvT (dead after QKV GEMM), 32M <= 48M
  float* part1 = (float*)wqkvT;

  // 1) converts / transposes
  convert_bf16_kernel<<<(T_SEQ * H_DIM / 4 + 255) / 256, 256, 0, stream>>>(
      hs, hsb, T_SEQ * H_DIM / 4);
  transpose_bf16_kernel<<<dim3(QKV_N / 64, H_DIM / 64), dim3(16, 16), 0, stream>>>(
      w_qkv, wqkvT, H_DIM, QKV_N);
  transpose_bf16_kernel<<<dim3(H_DIM / 64, H_DIM / 64), dim3(16, 16), 0, stream>>>(
      w_o, woT, H_DIM, H_DIM);
  // 2) QKV projection (256^2, full K)
  gemm256_kernel<true><<<dim3(QKV_N / 256, T_SEQ / 256, 1), 512, 0, stream>>>(
      hsb, wqkvT, qkvb, nullptr, T_SEQ, QKV_N, H_DIM, H_DIM);
  // 3) LN + RoPE (in place; q also scaled by 1/sqrt(HD))
  ln_rope_kernel<<<T_SEQ * (NH_Q + NKV_H) / 4, 256, 0, stream>>>(
      qkvb, positions, q_norm_w, k_norm_w);
  // 4) V transpose for PV B-operand
  vt_kernel<<<dim3(T_SEQ / 32, HD_ / 32, NKV_H), dim3(32, 8), 0, stream>>>(qkvb, vtb);
  // 5) flash attention (QBLK=128, 8 waves; paired Q-tiles: uniform work)
  attn_kernel<<<dim3(T_SEQ / 256, NH_Q), 512, 0, stream>>>(qkvb, vtb, attnb);
  // 6) output projection, split-K=2: grid 16x8x2 = 256 blocks (full coverage)
  gemm256_kernel<false><<<dim3(H_DIM / 256, T_SEQ / 256, 2), 512, 0, stream>>>(
      attnb, woT, out, part1, T_SEQ, H_DIM, H_DIM, H_DIM / 2);
  addf_kernel<<<(T_SEQ * H_DIM / 4 + 255) / 256, 256, 0, stream>>>(
      out, part1, T_SEQ * H_DIM / 4);
}